// Round 4
// baseline (528.958 us; speedup 1.0000x reference)
//
#include <hip/hip_runtime.h>
#include <hip/hip_bf16.h>

// QuantizedSimpleSSM — round 4: single-barrier double-buffered gemm pipeline.
// Numerics contract (absmax 0.0 since R2): every output element is a single
// fp32 FMA chain in strictly ascending k; recurrence is mul-then-add + q8.
// All changes here preserve that bitwise.

#define DINX 512
#define LSEQ 512
#define NDIM 512

__device__ __forceinline__ float q8(float x) {
    float xa = fabsf(x);
    float w  = __fadd_rn(xa, 1e-8f);
    int e = (int)((__float_as_uint(w) >> 23) & 0xFFu) - 127;   // floor(log2(w))
    e = e < -7 ? -7 : (e > 7 ? 7 : e);
    float p    = __int_as_float((unsigned)((e + 127) << 23));   // exact 2^e
    float invp = __int_as_float((unsigned)((127 - e) << 23));   // exact 2^-e
    // xa/p == xa*invp exactly (scaling by power of two), so this is bitwise
    // identical to the reference's divide.
    float t  = __fmul_rn(__fsub_rn(__fmul_rn(xa, invp), 1.0f), 8.0f);
    float m  = __fmul_rn(rintf(t), 0.125f);                     // half-to-even
    float r  = __fmul_rn(__fadd_rn(1.0f, m), p);
    return copysignf(r, x);
}

__global__ void quantk(const float* __restrict__ in, float* __restrict__ out, int n) {
    int i = blockIdx.x * blockDim.x + threadIdx.x;
    if (i < n) out[i] = q8(in[i]);
}

// out[c][r] = q8(in[r][c]) for three 512x512 matrices. grid (16,16,3), block 256.
__global__ __launch_bounds__(256) void quantT3(const float* __restrict__ B,
                                               const float* __restrict__ C,
                                               const float* __restrict__ D,
                                               float* __restrict__ Bqt,
                                               float* __restrict__ Cqt,
                                               float* __restrict__ Dqt) {
    __shared__ float tl[32][33];
    const float* in = blockIdx.z == 0 ? B : (blockIdx.z == 1 ? C : D);
    float* out      = blockIdx.z == 0 ? Bqt : (blockIdx.z == 1 ? Cqt : Dqt);
    const int r0 = blockIdx.y * 32, c0 = blockIdx.x * 32;
    const int x = threadIdx.x & 31, y = threadIdx.x >> 5;   // 32 x 8
#pragma unroll
    for (int i = 0; i < 32; i += 8)
        tl[y + i][x] = q8(in[(r0 + y + i) * 512 + c0 + x]);
    __syncthreads();
#pragma unroll
    for (int i = 0; i < 32; i += 8)
        out[(c0 + y + i) * 512 + r0 + x] = tl[x][y + i];
}

// One pipelined K-step (16 k's) with compile-time buffer index.
// Entering: buf[CUR] holds tile i (written last iter), regs hold tile i+1.
// Does: barrier; write tile i+1 -> buf[1-CUR]; issue loads tile i+2; compute tile i.
template <int CUR>
__device__ __forceinline__ void gemm_step(const float* __restrict__ xp,
                                          const float* __restrict__ wp,
                                          int k0, int KTOT,
                                          float4& x0, float4& x1, float4& w0, float4& w1,
                                          float (&acc)[8][8],
                                          float (*Xs)[16][128], float (*Ws)[16][128],
                                          int srow, int sseg8, int tx, int ty) {
    __syncthreads();
    if (k0 + 16 < KTOT) {
        *(float4*)&Xs[1 - CUR][srow][sseg8]     = x0;
        *(float4*)&Xs[1 - CUR][srow][sseg8 + 4] = x1;
        *(float4*)&Ws[1 - CUR][srow][sseg8]     = w0;
        *(float4*)&Ws[1 - CUR][srow][sseg8 + 4] = w1;
    }
    if (k0 + 32 < KTOT) {
        const float* xn = xp + (size_t)(k0 + 32) * 512;
        const float* wn = wp + (size_t)(k0 + 32) * 512;
        x0 = *(const float4*)xn; x1 = *(const float4*)(xn + 4);
        w0 = *(const float4*)wn; w1 = *(const float4*)(wn + 4);
    }
#pragma unroll
    for (int k = 0; k < 16; ++k) {
        float a[8], b[8];
        *(float4*)&a[0] = *(const float4*)&Xs[CUR][k][tx * 8];
        *(float4*)&a[4] = *(const float4*)&Xs[CUR][k][tx * 8 + 4];
        *(float4*)&b[0] = *(const float4*)&Ws[CUR][k][ty * 8];
        *(float4*)&b[4] = *(const float4*)&Ws[CUR][k][ty * 8 + 4];
#pragma unroll
        for (int i = 0; i < 8; ++i)
#pragma unroll
            for (int j = 0; j < 8; ++j)
                acc[i][j] = fmaf(a[i], b[j], acc[i][j]);
    }
}

// acc[i][j] += sum_k X[k][m0+tx*8+i] * W[k][n0+ty*8+j], k strictly ascending.
// X, W are [KTOT][512] row-major. KTOT must be a multiple of 32 (here: 512).
// Note on the unguarded prologue write to buf0: on a second call, stragglers
// from the previous pass are reading buf1 (tile 31, odd), never buf0 — safe.
__device__ __forceinline__ void gemm_pass(const float* __restrict__ X,
                                          const float* __restrict__ W,
                                          int m0, int n0, int KTOT,
                                          float (&acc)[8][8],
                                          float (*Xs)[16][128], float (*Ws)[16][128],
                                          int tid) {
    const int tx = tid & 15, ty = tid >> 4;
    const int srow = tid >> 4, sseg8 = (tid & 15) * 8;
    const float* xp = X + (size_t)srow * 512 + m0 + sseg8;
    const float* wp = W + (size_t)srow * 512 + n0 + sseg8;
    float4 x0 = *(const float4*)xp, x1 = *(const float4*)(xp + 4);
    float4 w0 = *(const float4*)wp, w1 = *(const float4*)(wp + 4);
    *(float4*)&Xs[0][srow][sseg8]     = x0;
    *(float4*)&Xs[0][srow][sseg8 + 4] = x1;
    *(float4*)&Ws[0][srow][sseg8]     = w0;
    *(float4*)&Ws[0][srow][sseg8 + 4] = w1;
    {   // load tile 1
        const float* xn = xp + 16 * 512;
        const float* wn = wp + 16 * 512;
        x0 = *(const float4*)xn; x1 = *(const float4*)(xn + 4);
        w0 = *(const float4*)wn; w1 = *(const float4*)(wn + 4);
    }
    for (int k0 = 0; k0 < KTOT; k0 += 32) {
        gemm_step<0>(xp, wp, k0,      KTOT, x0, x1, w0, w1, acc, Xs, Ws, srow, sseg8, tx, ty);
        gemm_step<1>(xp, wp, k0 + 16, KTOT, x0, x1, w0, w1, acc, Xs, Ws, srow, sseg8, tx, ty);
    }
}

// R[b][t][n] = sum_d u[b][d][t] * Bqt[d][n]. grid (4,4,32), block 256.
__global__ __launch_bounds__(256) void gemm_R(const float* __restrict__ u,
                                              const float* __restrict__ Bqt,
                                              float* __restrict__ R) {
    __shared__ float Xs[2][16][128];
    __shared__ float Ws[2][16][128];
    const int b  = blockIdx.z;
    const int t0 = blockIdx.x * 128, n0 = blockIdx.y * 128;
    const int tid = threadIdx.x;
    const int tx = tid & 15, ty = tid >> 4;
    const float* ub = u + (size_t)b * (DINX * LSEQ);
    float acc[8][8] = {};
    gemm_pass(ub, Bqt, t0, n0, DINX, acc, Xs, Ws, tid);
    float* Rb = R + (size_t)b * (LSEQ * NDIM);
#pragma unroll
    for (int i = 0; i < 8; ++i) {
        float* row = Rb + (size_t)(t0 + tx * 8 + i) * NDIM + n0 + ty * 8;
        *(float4*)row       = make_float4(acc[i][0], acc[i][1], acc[i][2], acc[i][3]);
        *(float4*)(row + 4) = make_float4(acc[i][4], acc[i][5], acc[i][6], acc[i][7]);
    }
}

// Per-(b, n-chunk) recurrence (bitwise np: mul-then-add, q8). Writes S[b][n][t].
// grid (32, 4), block 128 (thread = one n within the chunk).
__global__ __launch_bounds__(128) void recur(const float* __restrict__ R,
                                             const float* __restrict__ Aq,
                                             float* __restrict__ S) {
    __shared__ float tile[16][132];
    const int b  = blockIdx.x;
    const int n0 = blockIdx.y * 128;
    const int n  = threadIdx.x;                 // 0..127
    const float a = Aq[n0 + n];
    const float* Rb = R + (size_t)b * (LSEQ * NDIM) + n0;
    float* Sb = S + (size_t)b * (NDIM * LSEQ) + (size_t)n0 * LSEQ;
    float s = 0.0f;
    const int c = (n & 3) * 4;
    const int rbase = n >> 2;                   // 0..31
    for (int t0 = 0; t0 < LSEQ; t0 += 16) {
#pragma unroll
        for (int tt = 0; tt < 16; ++tt) {
            float r = Rb[(size_t)(t0 + tt) * NDIM + n];
            s = q8(__fadd_rn(__fmul_rn(s, a), r));
            tile[tt][n] = s;
        }
        __syncthreads();
#pragma unroll
        for (int p = 0; p < 4; ++p) {
            int row = p * 32 + rbase;
            float4 v = make_float4(tile[c + 0][row], tile[c + 1][row],
                                   tile[c + 2][row], tile[c + 3][row]);
            *(float4*)(Sb + (size_t)row * LSEQ + t0 + c) = v;
        }
        __syncthreads();
    }
}

// Y[b][o][t] = q8( (sum_n S[n][t]*Cqt[n][o]) + (sum_d u[d][t]*Dqt[d][o]) )
__global__ __launch_bounds__(256) void gemm_Y(const float* __restrict__ u,
                                              const float* __restrict__ S,
                                              const float* __restrict__ Cqt,
                                              const float* __restrict__ Dqt,
                                              float* __restrict__ Y) {
    __shared__ float Xs[2][16][128];
    __shared__ float Ws[2][16][128];
    const int b  = blockIdx.z;
    const int t0 = blockIdx.x * 128, o0 = blockIdx.y * 128;
    const int tid = threadIdx.x;
    const int tx = tid & 15, ty = tid >> 4;
    const float* Sb = S + (size_t)b * (NDIM * LSEQ);
    const float* ub = u + (size_t)b * (DINX * LSEQ);
    float acc[8][8] = {};
    float c1[8][8];
    gemm_pass(Sb, Cqt, t0, o0, NDIM, acc, Xs, Ws, tid);
#pragma unroll
    for (int i = 0; i < 8; ++i)
#pragma unroll
        for (int j = 0; j < 8; ++j) { c1[i][j] = acc[i][j]; acc[i][j] = 0.0f; }
    gemm_pass(ub, Dqt, t0, o0, DINX, acc, Xs, Ws, tid);

    float* Yb = Y + (size_t)b * (NDIM * LSEQ);
#pragma unroll
    for (int j = 0; j < 8; ++j) {
        float y0[4], y1[4];
#pragma unroll
        for (int i = 0; i < 4; ++i) y0[i] = q8(__fadd_rn(c1[i][j], acc[i][j]));
#pragma unroll
        for (int i = 0; i < 4; ++i) y1[i] = q8(__fadd_rn(c1[4 + i][j], acc[4 + i][j]));
        float* row = Yb + (size_t)(o0 + ty * 8 + j) * LSEQ + t0 + tx * 8;
        *(float4*)row       = make_float4(y0[0], y0[1], y0[2], y0[3]);
        *(float4*)(row + 4) = make_float4(y1[0], y1[1], y1[2], y1[3]);
    }
}

extern "C" void kernel_launch(void* const* d_in, const int* in_sizes, int n_in,
                              void* d_out, int out_size, void* d_ws, size_t ws_size,
                              hipStream_t stream) {
    const float* u = (const float*)d_in[0];   // (32, 512, 512)
    const float* A = (const float*)d_in[1];   // (512,)
    const float* B = (const float*)d_in[2];   // (512, 512)
    const float* C = (const float*)d_in[3];   // (512, 512)
    const float* D = (const float*)d_in[4];   // (512, 512)

    float* ws  = (float*)d_ws;
    float* Aq  = ws;                    // 512
    float* Bqt = Aq + 512;              // 262144  [d][n]
    float* Cqt = Bqt + 262144;          // 262144  [n][o]
    float* Dqt = Cqt + 262144;          // 262144  [d][o]
    float* R   = Dqt + 262144;          // 8388608 [b][t][n]
    float* S   = R + 8388608;           // 8388608 [b][n][t]
    float* Y   = (float*)d_out;         // 8388608 [b][o][t]

    quantk<<<2, 256, 0, stream>>>(A, Aq, 512);
    quantT3<<<dim3(16, 16, 3), 256, 0, stream>>>(B, C, D, Bqt, Cqt, Dqt);

    gemm_R<<<dim3(4, 4, 32), 256, 0, stream>>>(u, Bqt, R);
    recur<<<dim3(32, 4), 128, 0, stream>>>(R, Aq, S);
    gemm_Y<<<dim3(4, 4, 32), 256, 0, stream>>>(u, S, Cqt, Dqt, Y);
}

// Round 5
// 407.861 us; speedup vs baseline: 1.2969x; 1.2969x over previous
//
#include <hip/hip_runtime.h>
#include <hip/hip_bf16.h>

// QuantizedSimpleSSM — round 5: revert R4 double-buffer (VGPR blowup), keep R3
// single-buffer structure, fix LDS fragment layout: chunk-4 (2x2 of 4x4 per
// thread) removes 4-way bank conflicts on Xs and makes Ws reads quarter-wave
// broadcasts. Numerics contract (absmax 0.0 since R2): every output element is
// one fp32 FMA chain in strictly ascending k; recurrence mul-then-add + q8.

#define DINX 512
#define LSEQ 512
#define NDIM 512

__device__ __forceinline__ float q8(float x) {
    float xa = fabsf(x);
    float w  = __fadd_rn(xa, 1e-8f);
    int e = (int)((__float_as_uint(w) >> 23) & 0xFFu) - 127;   // floor(log2(w))
    e = e < -7 ? -7 : (e > 7 ? 7 : e);
    float p    = __int_as_float((unsigned)((e + 127) << 23));   // exact 2^e
    float invp = __int_as_float((unsigned)((127 - e) << 23));   // exact 2^-e
    float t  = __fmul_rn(__fsub_rn(__fmul_rn(xa, invp), 1.0f), 8.0f);
    float m  = __fmul_rn(rintf(t), 0.125f);                     // half-to-even
    float r  = __fmul_rn(__fadd_rn(1.0f, m), p);
    return copysignf(r, x);
}

__global__ void quantk(const float* __restrict__ in, float* __restrict__ out, int n) {
    int i = blockIdx.x * blockDim.x + threadIdx.x;
    if (i < n) out[i] = q8(in[i]);
}

// out[c][r] = q8(in[r][c]) for three 512x512 matrices. grid (16,16,3), block 256.
__global__ __launch_bounds__(256) void quantT3(const float* __restrict__ B,
                                               const float* __restrict__ C,
                                               const float* __restrict__ D,
                                               float* __restrict__ Bqt,
                                               float* __restrict__ Cqt,
                                               float* __restrict__ Dqt) {
    __shared__ float tl[32][33];
    const float* in = blockIdx.z == 0 ? B : (blockIdx.z == 1 ? C : D);
    float* out      = blockIdx.z == 0 ? Bqt : (blockIdx.z == 1 ? Cqt : Dqt);
    const int r0 = blockIdx.y * 32, c0 = blockIdx.x * 32;
    const int x = threadIdx.x & 31, y = threadIdx.x >> 5;   // 32 x 8
#pragma unroll
    for (int i = 0; i < 32; i += 8)
        tl[y + i][x] = q8(in[(r0 + y + i) * 512 + c0 + x]);
    __syncthreads();
#pragma unroll
    for (int i = 0; i < 32; i += 8)
        out[(c0 + y + i) * 512 + r0 + x] = tl[x][y + i];
}

// acc[p][i][q][j] += sum_k X[k][m0 + p*64 + tx*4 + i] * W[k][n0 + q*64 + ty*4 + j],
// k strictly ascending. X, W are [KTOT][512] row-major.
// LDS: Xs/Ws [16][128]; fragments are 16-B chunks at 4-dword stride ->
// 2-way bank aliasing max (free), Ws reads broadcast within quarter-waves.
__device__ __forceinline__ void gemm_pass(const float* __restrict__ X,
                                          const float* __restrict__ W,
                                          int m0, int n0, int KTOT,
                                          float (&acc)[2][4][2][4],
                                          float (*Xs)[128], float (*Ws)[128],
                                          int tid) {
    const int tx = tid & 15, ty = tid >> 4;
    const int srow = tid >> 4, sseg4 = (tid & 15) * 4;
    const float* xp = X + (size_t)srow * 512 + m0 + sseg4;
    const float* wp = W + (size_t)srow * 512 + n0 + sseg4;
    for (int k0 = 0; k0 < KTOT; k0 += 16) {
        float4 x0 = *(const float4*)xp;
        float4 x1 = *(const float4*)(xp + 64);
        float4 w0 = *(const float4*)wp;
        float4 w1 = *(const float4*)(wp + 64);
        xp += 16 * 512; wp += 16 * 512;
        __syncthreads();                 // prev-tile reads done before overwrite
        *(float4*)&Xs[srow][sseg4]      = x0;
        *(float4*)&Xs[srow][64 + sseg4] = x1;
        *(float4*)&Ws[srow][sseg4]      = w0;
        *(float4*)&Ws[srow][64 + sseg4] = w1;
        __syncthreads();
#pragma unroll
        for (int k = 0; k < 16; ++k) {
            float a[2][4], b[2][4];
            *(float4*)&a[0][0] = *(const float4*)&Xs[k][tx * 4];
            *(float4*)&a[1][0] = *(const float4*)&Xs[k][64 + tx * 4];
            *(float4*)&b[0][0] = *(const float4*)&Ws[k][ty * 4];
            *(float4*)&b[1][0] = *(const float4*)&Ws[k][64 + ty * 4];
#pragma unroll
            for (int p = 0; p < 2; ++p)
#pragma unroll
                for (int i = 0; i < 4; ++i)
#pragma unroll
                    for (int q = 0; q < 2; ++q)
#pragma unroll
                        for (int j = 0; j < 4; ++j)
                            acc[p][i][q][j] = fmaf(a[p][i], b[q][j], acc[p][i][q][j]);
        }
    }
}

// R[b][t][n] = sum_d u[b][d][t] * Bqt[d][n]. grid (4,4,32), block 256.
__global__ __launch_bounds__(256) void gemm_R(const float* __restrict__ u,
                                              const float* __restrict__ Bqt,
                                              float* __restrict__ R) {
    __shared__ float Xs[16][128];
    __shared__ float Ws[16][128];
    const int b  = blockIdx.z;
    const int t0 = blockIdx.x * 128, n0 = blockIdx.y * 128;
    const int tid = threadIdx.x;
    const int tx = tid & 15, ty = tid >> 4;
    const float* ub = u + (size_t)b * (DINX * LSEQ);
    float acc[2][4][2][4] = {};
    gemm_pass(ub, Bqt, t0, n0, DINX, acc, Xs, Ws, tid);
    float* Rb = R + (size_t)b * (LSEQ * NDIM);
#pragma unroll
    for (int p = 0; p < 2; ++p)
#pragma unroll
        for (int i = 0; i < 4; ++i) {
            float* row = Rb + (size_t)(t0 + p * 64 + tx * 4 + i) * NDIM + n0;
            *(float4*)(row + ty * 4)      = make_float4(acc[p][i][0][0], acc[p][i][0][1],
                                                        acc[p][i][0][2], acc[p][i][0][3]);
            *(float4*)(row + 64 + ty * 4) = make_float4(acc[p][i][1][0], acc[p][i][1][1],
                                                        acc[p][i][1][2], acc[p][i][1][3]);
        }
}

// Per-(b, n-chunk) recurrence (bitwise np: mul-then-add, q8). Writes S[b][n][t].
// grid (32, 4), block 128 (thread = one n within the chunk).
__global__ __launch_bounds__(128) void recur(const float* __restrict__ R,
                                             const float* __restrict__ Aq,
                                             float* __restrict__ S) {
    __shared__ float tile[16][132];
    const int b  = blockIdx.x;
    const int n0 = blockIdx.y * 128;
    const int n  = threadIdx.x;                 // 0..127
    const float a = Aq[n0 + n];
    const float* Rb = R + (size_t)b * (LSEQ * NDIM) + n0;
    float* Sb = S + (size_t)b * (NDIM * LSEQ) + (size_t)n0 * LSEQ;
    float s = 0.0f;
    const int c = (n & 3) * 4;
    const int rbase = n >> 2;                   // 0..31
    for (int t0 = 0; t0 < LSEQ; t0 += 16) {
#pragma unroll
        for (int tt = 0; tt < 16; ++tt) {
            float r = Rb[(size_t)(t0 + tt) * NDIM + n];
            s = q8(__fadd_rn(__fmul_rn(s, a), r));
            tile[tt][n] = s;
        }
        __syncthreads();
#pragma unroll
        for (int p = 0; p < 4; ++p) {
            int row = p * 32 + rbase;
            float4 v = make_float4(tile[c + 0][row], tile[c + 1][row],
                                   tile[c + 2][row], tile[c + 3][row]);
            *(float4*)(Sb + (size_t)row * LSEQ + t0 + c) = v;
        }
        __syncthreads();
    }
}

// Y[b][o][t] = q8( (sum_n S[n][t]*Cqt[n][o]) + (sum_d u[d][t]*Dqt[d][o]) )
__global__ __launch_bounds__(256) void gemm_Y(const float* __restrict__ u,
                                              const float* __restrict__ S,
                                              const float* __restrict__ Cqt,
                                              const float* __restrict__ Dqt,
                                              float* __restrict__ Y) {
    __shared__ float Xs[16][128];
    __shared__ float Ws[16][128];
    const int b  = blockIdx.z;
    const int t0 = blockIdx.x * 128, o0 = blockIdx.y * 128;
    const int tid = threadIdx.x;
    const int tx = tid & 15, ty = tid >> 4;
    const float* Sb = S + (size_t)b * (NDIM * LSEQ);
    const float* ub = u + (size_t)b * (DINX * LSEQ);
    float acc[2][4][2][4] = {};
    float c1[2][4][2][4];
    gemm_pass(Sb, Cqt, t0, o0, NDIM, acc, Xs, Ws, tid);
#pragma unroll
    for (int p = 0; p < 2; ++p)
#pragma unroll
        for (int i = 0; i < 4; ++i)
#pragma unroll
            for (int q = 0; q < 2; ++q)
#pragma unroll
                for (int j = 0; j < 4; ++j) {
                    c1[p][i][q][j] = acc[p][i][q][j];
                    acc[p][i][q][j] = 0.0f;
                }
    gemm_pass(ub, Dqt, t0, o0, DINX, acc, Xs, Ws, tid);

    float* Yb = Y + (size_t)b * (NDIM * LSEQ);
#pragma unroll
    for (int q = 0; q < 2; ++q)
#pragma unroll
        for (int j = 0; j < 4; ++j) {
            float y0[4], y1[4];
#pragma unroll
            for (int i = 0; i < 4; ++i) {
                y0[i] = q8(__fadd_rn(c1[0][i][q][j], acc[0][i][q][j]));
                y1[i] = q8(__fadd_rn(c1[1][i][q][j], acc[1][i][q][j]));
            }
            float* row = Yb + (size_t)(o0 + q * 64 + ty * 4 + j) * LSEQ + t0;
            *(float4*)(row + tx * 4)      = make_float4(y0[0], y0[1], y0[2], y0[3]);
            *(float4*)(row + 64 + tx * 4) = make_float4(y1[0], y1[1], y1[2], y1[3]);
        }
}

extern "C" void kernel_launch(void* const* d_in, const int* in_sizes, int n_in,
                              void* d_out, int out_size, void* d_ws, size_t ws_size,
                              hipStream_t stream) {
    const float* u = (const float*)d_in[0];   // (32, 512, 512)
    const float* A = (const float*)d_in[1];   // (512,)
    const float* B = (const float*)d_in[2];   // (512, 512)
    const float* C = (const float*)d_in[3];   // (512, 512)
    const float* D = (const float*)d_in[4];   // (512, 512)

    float* ws  = (float*)d_ws;
    float* Aq  = ws;                    // 512
    float* Bqt = Aq + 512;              // 262144  [d][n]
    float* Cqt = Bqt + 262144;          // 262144  [n][o]
    float* Dqt = Cqt + 262144;          // 262144  [d][o]
    float* R   = Dqt + 262144;          // 8388608 [b][t][n]
    float* S   = R + 8388608;           // 8388608 [b][n][t]
    float* Y   = (float*)d_out;         // 8388608 [b][o][t]

    quantk<<<2, 256, 0, stream>>>(A, Aq, 512);
    quantT3<<<dim3(16, 16, 3), 256, 0, stream>>>(B, C, D, Bqt, Cqt, Dqt);

    gemm_R<<<dim3(4, 4, 32), 256, 0, stream>>>(u, Bqt, R);
    recur<<<dim3(32, 4), 128, 0, stream>>>(R, Aq, S);
    gemm_Y<<<dim3(4, 4, 32), 256, 0, stream>>>(u, S, Cqt, Dqt, Y);
}